// Round 8
// baseline (1137.747 us; speedup 1.0000x reference)
//
#include <hip/hip_runtime.h>
#include <cstdint>
#include <cstddef>

// LSTM B=256,S=512,C=64,H=128, 2 layers, gates i,f,g,o (torch order).
// Round 8: DATAFLOW SYNC — no block-wide barrier in the hot loop at all.
// Each of the 8 waves owns 16 hidden cols (all 4 gates) and publishes a
// monotone per-wave LDS flag after writing its h-slice. A consumer gates
// each h A-fragment read only on the TWO producer waves of those 32 cols,
// so waves self-pace on true data readiness (slack ~3 steps via a 4-deep
// ring) instead of convoying through barrier->LDS->MFMA->trans phases in
// lockstep. Step is the lean fused form: 16 whh-MFMA + KK*4 wih-MFMA +
// 1-row elementwise. 128 blocks x 512 thr: blocks 0-63 layer 0 (4 batch
// rows), 64-127 layer 1 (y1 via global, per-wave chunk release: own-wave
// threadfence + counter-to-8).

#define S_LEN 512
#define B_SZ  256
#define C_IN  64
#define HDIM  128
#define NPAIR 64

using short8  = __attribute__((ext_vector_type(8))) short;   // 8 bf16
using float4v = __attribute__((ext_vector_type(4))) float;

__device__ __forceinline__ unsigned short f2b(float f) {
    union { float f; unsigned int u; } v; v.f = f;
    unsigned int u = v.u;
    return (unsigned short)((u + 0x7FFFu + ((u >> 16) & 1u)) >> 16);
}
__device__ __forceinline__ float sig_(float x) {
    return __builtin_amdgcn_rcpf(1.0f + __builtin_amdgcn_exp2f(x * -1.442695041f));
}
__device__ __forceinline__ float tanh_(float x) {
    return 1.0f - 2.0f * __builtin_amdgcn_rcpf(1.0f + __builtin_amdgcn_exp2f(x * 2.885390082f));
}

__global__ void prep_kernel(const float* __restrict__ x,
                            const float* __restrict__ wih0, const float* __restrict__ whh0,
                            const float* __restrict__ bih0, const float* __restrict__ bhh0,
                            const float* __restrict__ wih1, const float* __restrict__ whh1,
                            const float* __restrict__ bih1, const float* __restrict__ bhh1,
                            unsigned short* __restrict__ whh0_b, unsigned short* __restrict__ wih0_b,
                            unsigned short* __restrict__ whh1_b, unsigned short* __restrict__ wih1_b,
                            float* __restrict__ bias0, float* __restrict__ bias1,
                            unsigned short* __restrict__ xb) {
    int i = blockIdx.x * blockDim.x + threadIdx.x;
    if (i < B_SZ * S_LEN * C_IN) xb[i] = f2b(x[i]);
    if (i < 4 * HDIM * HDIM) {
        whh0_b[i] = f2b(whh0[i]);
        whh1_b[i] = f2b(whh1[i]);
        wih1_b[i] = f2b(wih1[i]);
    }
    if (i < 4 * HDIM * C_IN) wih0_b[i] = f2b(wih0[i]);
    if (i < 4 * HDIM) {
        bias0[i] = bih0[i] + bhh0[i];
        bias1[i] = bih1[i] + bhh1[i];
    }
}

// MFMA 16x16x32 bf16 frags (verified rounds 1-7):
//   A[m=lane&15][k=(lane>>4)*8+i], B == W[n=lane&15][k] 16B row chunk,
//   D[m=4*(lane>>4)+reg][n=lane&15]
// 4 batch rows at tile rows m=4b -> D element [0] of lane quad q is batch
// row q: every lane does exactly ONE elementwise group. A-frag kk covers
// hidden cols kk*32..kk*32+31 == producer waves 2kk, 2kk+1.
template<int KIN, bool IS_L0>
__device__ __forceinline__ void lstm_wave(
    unsigned short* ring,                         // 4 x 2048 shorts (4-deep h ring)
    int* flagsL,                                  // 8 per-wave monotone step flags
    const unsigned short* __restrict__ in_seq,    // L0: xb (B,S,C); L1: y1 (S,B,H)
    const unsigned short* __restrict__ wih_b,     // (512,KIN) bf16
    const unsigned short* __restrict__ whh_b,     // (512,128) bf16
    const float* __restrict__ bias,               // (512,) f32
    unsigned short* __restrict__ y1,              // L0 out (S,B,H) bf16
    float* __restrict__ out,                      // L1 out (B,H) f32
    int* __restrict__ flags_g, int blk) {
    constexpr int KK = KIN / 32;
    const int tid = threadIdx.x;
    const int w = tid >> 6, L = tid & 63, q = L >> 4, r = L & 15;
    const int boff = blk * 4, j = w * 16 + r;

    // register-resident weights (B-fragments)
    short8 whh[4][4], wih[4][KK];
    float bias_s[4];
#pragma unroll
    for (int g = 0; g < 4; ++g) {
        const int nrow = g * HDIM + j;
#pragma unroll
        for (int kk = 0; kk < 4; ++kk)
            whh[g][kk] = *(const short8*)(whh_b + (size_t)nrow * HDIM + kk * 32 + q * 8);
#pragma unroll
        for (int kk = 0; kk < KK; ++kk)
            wih[g][kk] = *(const short8*)(wih_b + (size_t)nrow * KIN + kk * 32 + q * 8);
        bias_s[g] = bias[g * HDIM + j];
    }

    for (int idx = tid; idx < 4 * 2048; idx += 512) ring[idx] = 0;  // h_{-1}=0 + pads
    if (tid < 8) flagsL[tid] = 0;
    __syncthreads();            // cold: ring/flag init visible (only barrier)

    float cf = 0.f;
    const int bload = boff + (r >> 2);      // A-row r -> batch row r/4 (r%4==0 valid)
    const unsigned short* base;
    size_t tstr;
    if constexpr (IS_L0) { base = in_seq + (size_t)bload * S_LEN * C_IN + q * 8; tstr = C_IN; }
    else                 { base = in_seq + (size_t)bload * HDIM + q * 8; tstr = (size_t)B_SZ * HDIM; }

    auto gate = [&](int ch) {   // L1: per-wave wait for y1 chunk ch (8 wave releases)
        if constexpr (!IS_L0) {
            while (__hip_atomic_load(flags_g + blk * 32 + ch, __ATOMIC_ACQUIRE,
                                     __HIP_MEMORY_SCOPE_AGENT) < 8)
                __builtin_amdgcn_s_sleep(1);
        }
    };
    auto loadin = [&](int t, short8* dst) {
#pragma unroll
        for (int kk = 0; kk < KK; ++kk)
            dst[kk] = *(const short8*)(base + (size_t)t * tstr + kk * 32);
    };

    gate(0);
    short8 xcur[KK], xnxt[KK];
    loadin(0, xcur);

    const int hwr = (j >> 3) * 128 + 32 * q + (j & 7);   // own h write offset

#pragma unroll 1
    for (int ch = 0; ch < 32; ++ch) {
#pragma unroll 4
        for (int s = 0; s < 16; ++s) {
            const int t = ch * 16 + s;
            // ---- dataflow-gated h_{t-1} A-frag reads (slot (t-1)&3) ----
            const int slotR = ((t + 3) & 3) * 2048;
            short8 hf[4];
#pragma unroll
            for (int kk = 0; kk < 4; ++kk) {
                while (__hip_atomic_load(flagsL + 2 * kk, __ATOMIC_ACQUIRE,
                                         __HIP_MEMORY_SCOPE_WORKGROUP) < t ||
                       __hip_atomic_load(flagsL + 2 * kk + 1, __ATOMIC_ACQUIRE,
                                         __HIP_MEMORY_SCOPE_WORKGROUP) < t) {}
                hf[kk] = *(const short8*)(ring + slotR + ((kk * 4 + q) * 16 + r) * 8);
            }
            // ---- gates = bias + h*Whh^T + x*Wih^T ----
            float4v a0 = {bias_s[0], bias_s[0], bias_s[0], bias_s[0]};
            float4v a1 = {bias_s[1], bias_s[1], bias_s[1], bias_s[1]};
            float4v a2 = {bias_s[2], bias_s[2], bias_s[2], bias_s[2]};
            float4v a3 = {bias_s[3], bias_s[3], bias_s[3], bias_s[3]};
#pragma unroll
            for (int kk = 0; kk < 4; ++kk) {
                a0 = __builtin_amdgcn_mfma_f32_16x16x32_bf16(hf[kk], whh[0][kk], a0, 0, 0, 0);
                a1 = __builtin_amdgcn_mfma_f32_16x16x32_bf16(hf[kk], whh[1][kk], a1, 0, 0, 0);
                a2 = __builtin_amdgcn_mfma_f32_16x16x32_bf16(hf[kk], whh[2][kk], a2, 0, 0, 0);
                a3 = __builtin_amdgcn_mfma_f32_16x16x32_bf16(hf[kk], whh[3][kk], a3, 0, 0, 0);
            }
#pragma unroll
            for (int kk = 0; kk < KK; ++kk) {
                a0 = __builtin_amdgcn_mfma_f32_16x16x32_bf16(xcur[kk], wih[0][kk], a0, 0, 0, 0);
                a1 = __builtin_amdgcn_mfma_f32_16x16x32_bf16(xcur[kk], wih[1][kk], a1, 0, 0, 0);
                a2 = __builtin_amdgcn_mfma_f32_16x16x32_bf16(xcur[kk], wih[2][kk], a2, 0, 0, 0);
                a3 = __builtin_amdgcn_mfma_f32_16x16x32_bf16(xcur[kk], wih[3][kk], a3, 0, 0, 0);
            }
            // ---- prefetch x/y1 for t+1 (chunk-gated for L1, per-wave) ----
            if (s == 15 && ch < 31) gate(ch + 1);
            const int tn = (t < S_LEN - 1) ? t + 1 : t;
            loadin(tn, xnxt);
            // ---- elementwise: 1 group/lane (batch row q, col j) ----
            const float iv = sig_(a0[0]);
            const float fv = sig_(a1[0]);
            const float gv = tanh_(a2[0]);
            const float ov = sig_(a3[0]);
            cf = fv * cf + iv * gv;
            const float hv = ov * tanh_(cf);
            const unsigned short hb = f2b(hv);
            ring[(t & 3) * 2048 + hwr] = hb;     // slot reuse safe: read-gate implies
                                                 // all flags >= t >= t-2 (depth 4)
            if constexpr (IS_L0)
                y1[((size_t)t * B_SZ + boff + q) * HDIM + j] = hb;
            else if (t == S_LEN - 1)
                out[(size_t)(boff + q) * HDIM + j] = hv;
            // publish own slice (after ring write; same-wave DS pipe is in-order)
            if (L == 0)
                __hip_atomic_store(flagsL + w, t + 1, __ATOMIC_RELEASE,
                                   __HIP_MEMORY_SCOPE_WORKGROUP);
            if constexpr (IS_L0) {
                if (s == 15) {
                    __threadfence();             // drain THIS wave's y1 stores
                    if (L == 0)
                        __hip_atomic_fetch_add(flags_g + blk * 32 + ch, 1,
                                               __ATOMIC_RELEASE, __HIP_MEMORY_SCOPE_AGENT);
                }
            }
#pragma unroll
            for (int kk = 0; kk < KK; ++kk) xcur[kk] = xnxt[kk];
        }
    }
}

__global__ __launch_bounds__(512, 2)
void lstm_pipe(const unsigned short* __restrict__ xb,
               const unsigned short* __restrict__ wih0_b, const unsigned short* __restrict__ whh0_b,
               const float* __restrict__ bias0,
               const unsigned short* __restrict__ wih1_b, const unsigned short* __restrict__ whh1_b,
               const float* __restrict__ bias1,
               unsigned short* __restrict__ y1, float* __restrict__ out,
               int* __restrict__ flags_g) {
    __shared__ __align__(16) unsigned short ring[4 * 2048];   // 16 KB
    __shared__ int flagsL[8];
    if (blockIdx.x < NPAIR)
        lstm_wave<C_IN, true>(ring, flagsL, xb, wih0_b, whh0_b, bias0, y1, nullptr,
                              flags_g, blockIdx.x);
    else
        lstm_wave<HDIM, false>(ring, flagsL, y1, wih1_b, whh1_b, bias1, nullptr, out,
                               flags_g, blockIdx.x - NPAIR);
}

// ---- workspace layout (bytes) ----
//       0 : whh0_b 131072
//  131072 : wih0_b  65536
//  196608 : whh1_b 131072
//  327680 : wih1_b 131072
//  458752 : bias0    2048
//  460800 : bias1    2048
//  462848 : flags    8192  (64 blocks x 32 chunk counters, memset 0 per launch)
//  524288 : xb   16777216
// 17301504: y1   33554432

extern "C" void kernel_launch(void* const* d_in, const int* in_sizes, int n_in,
                              void* d_out, int out_size, void* d_ws, size_t ws_size,
                              hipStream_t stream) {
    const float* x    = (const float*)d_in[0];
    const float* wih0 = (const float*)d_in[1];
    const float* whh0 = (const float*)d_in[2];
    const float* bih0 = (const float*)d_in[3];
    const float* bhh0 = (const float*)d_in[4];
    const float* wih1 = (const float*)d_in[5];
    const float* whh1 = (const float*)d_in[6];
    const float* bih1 = (const float*)d_in[7];
    const float* bhh1 = (const float*)d_in[8];

    char* ws = (char*)d_ws;
    unsigned short* whh0_b = (unsigned short*)(ws + 0);
    unsigned short* wih0_b = (unsigned short*)(ws + 131072);
    unsigned short* whh1_b = (unsigned short*)(ws + 196608);
    unsigned short* wih1_b = (unsigned short*)(ws + 327680);
    float*          bias0  = (float*)(ws + 458752);
    float*          bias1  = (float*)(ws + 460800);
    int*            flags  = (int*)(ws + 462848);
    unsigned short* xb     = (unsigned short*)(ws + 524288);
    unsigned short* y1     = (unsigned short*)(ws + 17301504);

    hipMemsetAsync(flags, 0, 8192, stream);

    prep_kernel<<<(B_SZ * S_LEN * C_IN + 255) / 256, 256, 0, stream>>>(
        x, wih0, whh0, bih0, bhh0, wih1, whh1, bih1, bhh1,
        whh0_b, wih0_b, whh1_b, wih1_b, bias0, bias1, xb);

    lstm_pipe<<<dim3(2 * NPAIR), dim3(512), 0, stream>>>(
        xb, wih0_b, whh0_b, bias0, wih1_b, whh1_b, bias1, y1, (float*)d_out, flags);
}